// Round 3
// baseline (614.880 us; speedup 1.0000x reference)
//
#include <hip/hip_runtime.h>

#define KNBR 8

// Pack each coarse point as {x,y,z,|xyz|^2, nx,ny,nz,|nrm|^2} (two float4s)
__global__ __launch_bounds__(256) void pack_kernel(
    const float* __restrict__ xa, const float* __restrict__ na, int ca,
    const float* __restrict__ xb, const float* __restrict__ nb, int cb,
    const float* __restrict__ xc, const float* __restrict__ nc_, int cc,
    float* __restrict__ pa, float* __restrict__ pb, float* __restrict__ pc)
{
#pragma clang fp contract(off)
    int t = blockIdx.x * blockDim.x + threadIdx.x;
    const float* xs; const float* ns; float* dst; int i;
    if (t < ca)            { xs = xa; ns = na;  dst = pa; i = t; }
    else if (t < ca + cb)  { xs = xb; ns = nb;  dst = pb; i = t - ca; }
    else if (t < ca+cb+cc) { xs = xc; ns = nc_; dst = pc; i = t - ca - cb; }
    else return;
    float x = xs[3*i], y = xs[3*i+1], z = xs[3*i+2];
    float u = ns[3*i], v = ns[3*i+1], w = ns[3*i+2];
    float4 r0 = make_float4(x, y, z, (x*x + y*y) + z*z);
    float4 r1 = make_float4(u, v, w, (u*u + v*v) + w*w);
    reinterpret_cast<float4*>(dst)[2*i]     = r0;
    reinterpret_cast<float4*>(dst)[2*i + 1] = r1;
}

// L lanes per fine point. Each lane scans NC/L candidates into a private
// sorted top-8 (static indices only), then log2(L)-level shfl_xor bitonic
// merge. Early-skip: v = dx + sigmoid(dn) >= dx + 0.5 exactly (sigmoid >= 0.5
// for dn >= 0, monotone correctly-rounded add), so when no lane in the wave
// has dx + 0.5 < d[7], the nrm/exp/div/insert path is skipped losslessly.
template<int L, int LOG2L>
__global__ __launch_bounds__(256) void topk_kernel(
    const float* __restrict__ xyzF, const float* __restrict__ nrmF,
    const float* __restrict__ packC, int NF, int NC,
    int* __restrict__ outIdx, float* __restrict__ outW)
{
#pragma clang fp contract(off)
    const int lane = threadIdx.x & (L - 1);
    const int grp  = (blockIdx.x * blockDim.x + threadIdx.x) >> LOG2L; // [0, 2*NF)
    const int b    = grp >= NF ? 1 : 0;

    const float* fp = xyzF + (size_t)grp * 3;
    float fx = fp[0], fy = fp[1], fz = fp[2];
    const float* gp = nrmF + (size_t)grp * 3;
    float gx = gp[0], gy = gp[1], gz = gp[2];
    float sax = (fx*fx + fy*fy) + fz*fz;
    float san = (gx*gx + gy*gy) + gz*gz;

    float d[KNBR]; int id[KNBR];
#pragma unroll
    for (int j = 0; j < KNBR; ++j) { d[j] = 3.402823466e38f; id[j] = 0; }

    const float4* base = reinterpret_cast<const float4*>(packC) + (size_t)b * NC * 2;
    for (int s = lane; s < NC; s += L) {
        float4 c0 = base[2*s];
        float4 c1 = base[2*s + 1];
        float dot = (fx*c0.x + fy*c0.y) + fz*c0.z;
        float d2  = (sax + c0.w) - 2.0f*dot;
        float dx  = sqrtf(fmaxf(d2, 0.0f));
        // exact wave-wide prune: v >= dx + 0.5 always
        if (__ballot(dx + 0.5f < d[KNBR-1])) {
            float dtn = (gx*c1.x + gy*c1.y) + gz*c1.z;
            float d2n = (san + c1.w) - 2.0f*dtn;
            float dn  = sqrtf(fmaxf(d2n, 0.0f));
            float sg  = 1.0f / (1.0f + expf(-dn));
            float v   = dx + sg;
            if (v < d[KNBR-1]) {
#pragma unroll
                for (int j = KNBR-1; j >= 1; --j) {
                    bool lt  = v < d[j];
                    bool lt2 = v < d[j-1];
                    float ndv = lt ? (lt2 ? d[j-1] : v) : d[j];
                    int   niv = lt ? (lt2 ? id[j-1] : s) : id[j];
                    d[j] = ndv; id[j] = niv;
                }
                if (v < d[0]) { d[0] = v; id[0] = s; }
            }
        }
    }

    // merge sorted top-8 lists across the L-lane group (keep-low-8 bitonic)
#pragma unroll
    for (int m = 1; m < L; m <<= 1) {
        float pd[KNBR]; int pi[KNBR];
#pragma unroll
        for (int j = 0; j < KNBR; ++j) {
            pd[j] = __shfl_xor(d[j], m);
            pi[j] = __shfl_xor(id[j], m);
        }
        float nd[KNBR]; int ni[KNBR];
#pragma unroll
        for (int j = 0; j < KNBR; ++j) {
            bool t = pd[KNBR-1-j] < d[j];
            nd[j] = t ? pd[KNBR-1-j] : d[j];
            ni[j] = t ? pi[KNBR-1-j] : id[j];
        }
#define CE(A,B_) { bool sw = nd[B_] < nd[A];                       \
                   float lo = sw ? nd[B_] : nd[A];                 \
                   float hi = sw ? nd[A] : nd[B_];                 \
                   int li = sw ? ni[B_] : ni[A];                   \
                   int hi2 = sw ? ni[A] : ni[B_];                  \
                   nd[A] = lo; nd[B_] = hi; ni[A] = li; ni[B_] = hi2; }
        CE(0,4) CE(1,5) CE(2,6) CE(3,7)
        CE(0,2) CE(1,3) CE(4,6) CE(5,7)
        CE(0,1) CE(2,3) CE(4,5) CE(6,7)
#undef CE
#pragma unroll
        for (int j = 0; j < KNBR; ++j) { d[j] = nd[j]; id[j] = ni[j]; }
    }

    if (lane == 0) {
        float r[KNBR]; float sum = 0.f;
#pragma unroll
        for (int j = 0; j < KNBR; ++j) { r[j] = 1.0f / (d[j] + 1e-8f); sum += r[j]; }
        int*   oi = outIdx + (size_t)grp * KNBR;
        float* ow = outW   + (size_t)grp * KNBR;
#pragma unroll
        for (int j = 0; j < KNBR; ++j) { oi[j] = id[j]; ow[j] = r[j] / sum; }
    }
}

// 4 points per block; 64 lanes per point, float4 per lane (C=256).
__global__ __launch_bounds__(256) void interp_kernel(
    const float* __restrict__ p1, const float* __restrict__ p2,
    const int* __restrict__ idx, const float* __restrict__ w,
    int NF, int NC, float* __restrict__ out)
{
    const int pt = blockIdx.x * 4 + (threadIdx.x >> 6);  // [0, 2*NF), wave-uniform
    const int c4 = threadIdx.x & 63;
    const int b  = pt >= NF ? 1 : 0;
    const int*   ip = idx + (size_t)pt * KNBR;
    const float* wp = w   + (size_t)pt * KNBR;
    const float4* p2b = reinterpret_cast<const float4*>(p2) + (size_t)b * NC * 64;
    float4 acc = make_float4(0.f, 0.f, 0.f, 0.f);
#pragma unroll
    for (int j = 0; j < KNBR; ++j) {
        int   ii = ip[j];
        float ww = wp[j];
        float4 r = p2b[(size_t)ii * 64 + c4];
        acc.x += ww * r.x; acc.y += ww * r.y;
        acc.z += ww * r.z; acc.w += ww * r.w;
    }
    float4 a = reinterpret_cast<const float4*>(p1)[(size_t)pt * 64 + c4];
    float4 o;
    o.x = (fmaxf(a.x, acc.x) + (a.x + acc.x) * 0.5f) * 0.5f;
    o.y = (fmaxf(a.y, acc.y) + (a.y + acc.y) * 0.5f) * 0.5f;
    o.z = (fmaxf(a.z, acc.z) + (a.z + acc.z) * 0.5f) * 0.5f;
    o.w = (fmaxf(a.w, acc.w) + (a.w + acc.w) * 0.5f) * 0.5f;
    reinterpret_cast<float4*>(out)[(size_t)pt * 64 + c4] = o;
}

extern "C" void kernel_launch(void* const* d_in, const int* in_sizes, int n_in,
                              void* d_out, int out_size, void* d_ws, size_t ws_size,
                              hipStream_t stream)
{
    const float* xyz0  = (const float*)d_in[0];
    const float* nrm0  = (const float*)d_in[1];
    const float* feat0 = (const float*)d_in[2];
    const float* xyz1  = (const float*)d_in[3];
    const float* nrm1  = (const float*)d_in[4];
    const float* feat1 = (const float*)d_in[5];
    const float* xyz2  = (const float*)d_in[6];
    const float* nrm2  = (const float*)d_in[7];
    const float* feat2 = (const float*)d_in[8];
    const float* xyz3  = (const float*)d_in[9];
    const float* nrm3  = (const float*)d_in[10];
    const float* feat3 = (const float*)d_in[11];

    const int B = 2, C = 256;
    const int N0 = 16384, N1 = 4096, N2 = 1024, N3 = 256;

    float* ws = (float*)d_ws;
    size_t off = 0;
    float* pack1 = ws + off; off += (size_t)B*N1*8;   // coarse for stage 2
    float* pack2 = ws + off; off += (size_t)B*N2*8;   // coarse for stage 1
    float* pack3 = ws + off; off += (size_t)B*N3*8;   // coarse for stage 0
    int*   idx0  = (int*)(ws + off); off += (size_t)B*N2*KNBR;
    float* w0    = ws + off;         off += (size_t)B*N2*KNBR;
    int*   idx1  = (int*)(ws + off); off += (size_t)B*N1*KNBR;
    float* w1    = ws + off;         off += (size_t)B*N1*KNBR;
    int*   idx2  = (int*)(ws + off); off += (size_t)B*N0*KNBR;
    float* w2    = ws + off;         off += (size_t)B*N0*KNBR;
    float* x0    = ws + off;         off += (size_t)B*N2*C;
    float* x1    = ws + off;         off += (size_t)B*N1*C;

    int packTot = B * (N1 + N2 + N3);
    pack_kernel<<<(packTot + 255)/256, 256, 0, stream>>>(
        xyz1, nrm1, B*N1, xyz2, nrm2, B*N2, xyz3, nrm3, B*N3,
        pack1, pack2, pack3);

    // top-k is feature-independent: run all three up front.
    // Stage 2 (16384<-4096): L=8 -> 4096 waves, halved duplicate L2 reads.
    topk_kernel<8,3> <<<(B*N0*8)/256,  256, 0, stream>>>(xyz0, nrm0, pack1, N0, N1, idx2, w2);
    topk_kernel<16,4><<<(B*N1*16)/256, 256, 0, stream>>>(xyz1, nrm1, pack2, N1, N2, idx1, w1);
    topk_kernel<16,4><<<(B*N2*16)/256, 256, 0, stream>>>(xyz2, nrm2, pack3, N2, N3, idx0, w0);

    // feature chain: feat3 -> x0 -> x1 -> d_out
    interp_kernel<<<(B*N2)/4, 256, 0, stream>>>(feat2, feat3, idx0, w0, N2, N3, x0);
    interp_kernel<<<(B*N1)/4, 256, 0, stream>>>(feat1, x0,    idx1, w1, N1, N2, x1);
    interp_kernel<<<(B*N0)/4, 256, 0, stream>>>(feat0, x1,    idx2, w2, N0, N1, (float*)d_out);
}

// Round 4
// 344.009 us; speedup vs baseline: 1.7874x; 1.7874x over previous
//
#include <hip/hip_runtime.h>

#define KNBR 8

// Pack each coarse point as {x,y,z,|xyz|^2, nx,ny,nz,|nrm|^2} (two float4s)
__global__ __launch_bounds__(256) void pack_kernel(
    const float* __restrict__ xa, const float* __restrict__ na, int ca,
    const float* __restrict__ xb, const float* __restrict__ nb, int cb,
    const float* __restrict__ xc, const float* __restrict__ nc_, int cc,
    float* __restrict__ pa, float* __restrict__ pb, float* __restrict__ pc)
{
#pragma clang fp contract(off)
    int t = blockIdx.x * blockDim.x + threadIdx.x;
    const float* xs; const float* ns; float* dst; int i;
    if (t < ca)            { xs = xa; ns = na;  dst = pa; i = t; }
    else if (t < ca + cb)  { xs = xb; ns = nb;  dst = pb; i = t - ca; }
    else if (t < ca+cb+cc) { xs = xc; ns = nc_; dst = pc; i = t - ca - cb; }
    else return;
    float x = xs[3*i], y = xs[3*i+1], z = xs[3*i+2];
    float u = ns[3*i], v = ns[3*i+1], w = ns[3*i+2];
    float4 r0 = make_float4(x, y, z, (x*x + y*y) + z*z);
    float4 r1 = make_float4(u, v, w, (u*u + v*v) + w*w);
    reinterpret_cast<float4*>(dst)[2*i]     = r0;
    reinterpret_cast<float4*>(dst)[2*i + 1] = r1;
}

// comparator on (Va,Ia): full exchange, ascending
#define CEX(V, I, A, B) { bool sw_ = V[B] < V[A];                       \
    float lo_ = sw_ ? V[B] : V[A]; float hi_ = sw_ ? V[A] : V[B];       \
    int   li_ = sw_ ? I[B] : I[A]; int   hj_ = sw_ ? I[A] : I[B];       \
    V[A] = lo_; V[B] = hi_; I[A] = li_; I[B] = hj_; }

// L lanes per fine point. Each lane scans NC/L candidates in chunks of 8:
// compute 8 keys unconditionally, sort the 8 (Batcher, 19 comparators),
// merge-keep-low-8 with the running sorted top-8 (8 + 12 comparators).
// No divergent insert path: wave-OR divergence made per-candidate guarded
// insertion fire ~every iteration (measured 253 inst/iter); this is ~55.
template<int L>
__global__ __launch_bounds__(256) void topk_kernel(
    const float* __restrict__ xyzF, const float* __restrict__ nrmF,
    const float* __restrict__ packC, int NF, int NC,
    int* __restrict__ outIdx, float* __restrict__ outW)
{
    const int lane = threadIdx.x & (L - 1);
    const int grp  = (blockIdx.x * blockDim.x + threadIdx.x) / L;   // [0, 2*NF)
    const int b    = grp >= NF ? 1 : 0;

    const float* fp = xyzF + (size_t)grp * 3;
    float fx = fp[0], fy = fp[1], fz = fp[2];
    const float* gp = nrmF + (size_t)grp * 3;
    float gx = gp[0], gy = gp[1], gz = gp[2];
    float sax = fmaf(fx, fx, fmaf(fy, fy, fz * fz));
    float san = fmaf(gx, gx, fmaf(gy, gy, gz * gz));

    float d[KNBR]; int id[KNBR];
#pragma unroll
    for (int j = 0; j < KNBR; ++j) { d[j] = 3.402823466e38f; id[j] = 0; }

    const float4* base = reinterpret_cast<const float4*>(packC) + (size_t)b * NC * 2;
    const int nch = NC / (8 * L);
    for (int cc = 0; cc < nch; ++cc) {
        const int s0 = cc * (8 * L) + lane;
        const float4* p = base + (size_t)s0 * 2;
        float4 q0[8], q1[8];
#pragma unroll
        for (int k = 0; k < 8; ++k) { q0[k] = p[2*L*k]; q1[k] = p[2*L*k + 1]; }

        float cv[8]; int ci[8];
#pragma unroll
        for (int k = 0; k < 8; ++k) {
            float dot = fmaf(fx, q0[k].x, fmaf(fy, q0[k].y, fz * q0[k].z));
            float d2  = fmaf(-2.0f, dot, sax + q0[k].w);
            float dxx = __builtin_amdgcn_sqrtf(fmaxf(d2, 0.0f));
            float dtn = fmaf(gx, q1[k].x, fmaf(gy, q1[k].y, gz * q1[k].z));
            float d2n = fmaf(-2.0f, dtn, san + q1[k].w);
            float dnn = __builtin_amdgcn_sqrtf(fmaxf(d2n, 0.0f));
            float sg  = __builtin_amdgcn_rcpf(1.0f + __expf(-dnn));
            cv[k] = dxx + sg;
            ci[k] = s0 + k * L;
        }

        // Batcher odd-even mergesort, 8 keys, 19 comparators -> ascending
        CEX(cv,ci,0,1) CEX(cv,ci,2,3) CEX(cv,ci,4,5) CEX(cv,ci,6,7)
        CEX(cv,ci,0,2) CEX(cv,ci,1,3) CEX(cv,ci,4,6) CEX(cv,ci,5,7)
        CEX(cv,ci,1,2) CEX(cv,ci,5,6)
        CEX(cv,ci,0,4) CEX(cv,ci,1,5) CEX(cv,ci,2,6) CEX(cv,ci,3,7)
        CEX(cv,ci,2,4) CEX(cv,ci,3,5)
        CEX(cv,ci,1,2) CEX(cv,ci,3,4) CEX(cv,ci,5,6)

        // keep-low-8 of (d sorted asc, cv sorted asc): lo[i]=min(d[i],cv[7-i])
        float nd[KNBR]; int ni[KNBR];
#pragma unroll
        for (int i = 0; i < KNBR; ++i) {
            bool t = cv[KNBR-1-i] < d[i];
            nd[i] = t ? cv[KNBR-1-i] : d[i];
            ni[i] = t ? ci[KNBR-1-i] : id[i];
        }
        // nd is bitonic; clean to ascending (12 comparators)
        CEX(nd,ni,0,4) CEX(nd,ni,1,5) CEX(nd,ni,2,6) CEX(nd,ni,3,7)
        CEX(nd,ni,0,2) CEX(nd,ni,1,3) CEX(nd,ni,4,6) CEX(nd,ni,5,7)
        CEX(nd,ni,0,1) CEX(nd,ni,2,3) CEX(nd,ni,4,5) CEX(nd,ni,6,7)
#pragma unroll
        for (int j = 0; j < KNBR; ++j) { d[j] = nd[j]; id[j] = ni[j]; }
    }

    // merge sorted top-8 lists across the L-lane group (keep-low-8 bitonic)
#pragma unroll
    for (int m = 1; m < L; m <<= 1) {
        float pd[KNBR]; int pi[KNBR];
#pragma unroll
        for (int j = 0; j < KNBR; ++j) {
            pd[j] = __shfl_xor(d[j], m);
            pi[j] = __shfl_xor(id[j], m);
        }
        float nd[KNBR]; int ni[KNBR];
#pragma unroll
        for (int j = 0; j < KNBR; ++j) {
            bool t = pd[KNBR-1-j] < d[j];
            nd[j] = t ? pd[KNBR-1-j] : d[j];
            ni[j] = t ? pi[KNBR-1-j] : id[j];
        }
        CEX(nd,ni,0,4) CEX(nd,ni,1,5) CEX(nd,ni,2,6) CEX(nd,ni,3,7)
        CEX(nd,ni,0,2) CEX(nd,ni,1,3) CEX(nd,ni,4,6) CEX(nd,ni,5,7)
        CEX(nd,ni,0,1) CEX(nd,ni,2,3) CEX(nd,ni,4,5) CEX(nd,ni,6,7)
#pragma unroll
        for (int j = 0; j < KNBR; ++j) { d[j] = nd[j]; id[j] = ni[j]; }
    }

    if (lane == 0) {
        float r[KNBR]; float sum = 0.f;
#pragma unroll
        for (int j = 0; j < KNBR; ++j) { r[j] = 1.0f / (d[j] + 1e-8f); sum += r[j]; }
        int*   oi = outIdx + (size_t)grp * KNBR;
        float* ow = outW   + (size_t)grp * KNBR;
#pragma unroll
        for (int j = 0; j < KNBR; ++j) { oi[j] = id[j]; ow[j] = r[j] / sum; }
    }
}

// 4 points per block; 64 lanes per point, float4 per lane (C=256).
__global__ __launch_bounds__(256) void interp_kernel(
    const float* __restrict__ p1, const float* __restrict__ p2,
    const int* __restrict__ idx, const float* __restrict__ w,
    int NF, int NC, float* __restrict__ out)
{
    const int pt = blockIdx.x * 4 + (threadIdx.x >> 6);  // [0, 2*NF), wave-uniform
    const int c4 = threadIdx.x & 63;
    const int b  = pt >= NF ? 1 : 0;
    const int*   ip = idx + (size_t)pt * KNBR;
    const float* wp = w   + (size_t)pt * KNBR;
    const float4* p2b = reinterpret_cast<const float4*>(p2) + (size_t)b * NC * 64;
    float4 acc = make_float4(0.f, 0.f, 0.f, 0.f);
#pragma unroll
    for (int j = 0; j < KNBR; ++j) {
        int   ii = ip[j];
        float ww = wp[j];
        float4 r = p2b[(size_t)ii * 64 + c4];
        acc.x += ww * r.x; acc.y += ww * r.y;
        acc.z += ww * r.z; acc.w += ww * r.w;
    }
    float4 a = reinterpret_cast<const float4*>(p1)[(size_t)pt * 64 + c4];
    float4 o;
    o.x = (fmaxf(a.x, acc.x) + (a.x + acc.x) * 0.5f) * 0.5f;
    o.y = (fmaxf(a.y, acc.y) + (a.y + acc.y) * 0.5f) * 0.5f;
    o.z = (fmaxf(a.z, acc.z) + (a.z + acc.z) * 0.5f) * 0.5f;
    o.w = (fmaxf(a.w, acc.w) + (a.w + acc.w) * 0.5f) * 0.5f;
    reinterpret_cast<float4*>(out)[(size_t)pt * 64 + c4] = o;
}

extern "C" void kernel_launch(void* const* d_in, const int* in_sizes, int n_in,
                              void* d_out, int out_size, void* d_ws, size_t ws_size,
                              hipStream_t stream)
{
    const float* xyz0  = (const float*)d_in[0];
    const float* nrm0  = (const float*)d_in[1];
    const float* feat0 = (const float*)d_in[2];
    const float* xyz1  = (const float*)d_in[3];
    const float* nrm1  = (const float*)d_in[4];
    const float* feat1 = (const float*)d_in[5];
    const float* xyz2  = (const float*)d_in[6];
    const float* nrm2  = (const float*)d_in[7];
    const float* feat2 = (const float*)d_in[8];
    const float* xyz3  = (const float*)d_in[9];
    const float* nrm3  = (const float*)d_in[10];
    const float* feat3 = (const float*)d_in[11];

    const int B = 2, C = 256;
    const int N0 = 16384, N1 = 4096, N2 = 1024, N3 = 256;

    float* ws = (float*)d_ws;
    size_t off = 0;
    float* pack1 = ws + off; off += (size_t)B*N1*8;   // coarse for stage 2
    float* pack2 = ws + off; off += (size_t)B*N2*8;   // coarse for stage 1
    float* pack3 = ws + off; off += (size_t)B*N3*8;   // coarse for stage 0
    int*   idx0  = (int*)(ws + off); off += (size_t)B*N2*KNBR;
    float* w0    = ws + off;         off += (size_t)B*N2*KNBR;
    int*   idx1  = (int*)(ws + off); off += (size_t)B*N1*KNBR;
    float* w1    = ws + off;         off += (size_t)B*N1*KNBR;
    int*   idx2  = (int*)(ws + off); off += (size_t)B*N0*KNBR;
    float* w2    = ws + off;         off += (size_t)B*N0*KNBR;
    float* x0    = ws + off;         off += (size_t)B*N2*C;
    float* x1    = ws + off;         off += (size_t)B*N1*C;

    int packTot = B * (N1 + N2 + N3);
    pack_kernel<<<(packTot + 255)/256, 256, 0, stream>>>(
        xyz1, nrm1, B*N1, xyz2, nrm2, B*N2, xyz3, nrm3, B*N3,
        pack1, pack2, pack3);

    // top-k is feature-independent: run all three up front. L=8 everywhere
    // (NC divisible by 8*L: 4096/64, 1024/64, 256/64).
    topk_kernel<8><<<(B*N0*8)/256, 256, 0, stream>>>(xyz0, nrm0, pack1, N0, N1, idx2, w2);
    topk_kernel<8><<<(B*N1*8)/256, 256, 0, stream>>>(xyz1, nrm1, pack2, N1, N2, idx1, w1);
    topk_kernel<8><<<(B*N2*8)/256, 256, 0, stream>>>(xyz2, nrm2, pack3, N2, N3, idx0, w0);

    // feature chain: feat3 -> x0 -> x1 -> d_out
    interp_kernel<<<(B*N2)/4, 256, 0, stream>>>(feat2, feat3, idx0, w0, N2, N3, x0);
    interp_kernel<<<(B*N1)/4, 256, 0, stream>>>(feat1, x0,    idx1, w1, N1, N2, x1);
    interp_kernel<<<(B*N0)/4, 256, 0, stream>>>(feat0, x1,    idx2, w2, N0, N1, (float*)d_out);
}

// Round 8
// 291.011 us; speedup vs baseline: 2.1129x; 1.1821x over previous
//
#include <hip/hip_runtime.h>

#define KNBR 8

// Pack each coarse point as {-2x,-2y,-2z,|xyz|^2, -2nx,-2ny,-2nz,|nrm|^2}
// so the hot loop computes d2 = fma(fx,cx, fma(fy,cy, fma(fz,cz, sax+cw))).
__global__ __launch_bounds__(256) void pack_kernel(
    const float* __restrict__ xa, const float* __restrict__ na, int ca,
    const float* __restrict__ xb, const float* __restrict__ nb, int cb,
    const float* __restrict__ xc, const float* __restrict__ nc_, int cc,
    float* __restrict__ pa, float* __restrict__ pb, float* __restrict__ pc)
{
#pragma clang fp contract(off)
    int t = blockIdx.x * blockDim.x + threadIdx.x;
    const float* xs; const float* ns; float* dst; int i;
    if (t < ca)            { xs = xa; ns = na;  dst = pa; i = t; }
    else if (t < ca + cb)  { xs = xb; ns = nb;  dst = pb; i = t - ca; }
    else if (t < ca+cb+cc) { xs = xc; ns = nc_; dst = pc; i = t - ca - cb; }
    else return;
    float x = xs[3*i], y = xs[3*i+1], z = xs[3*i+2];
    float u = ns[3*i], v = ns[3*i+1], w = ns[3*i+2];
    float4 r0 = make_float4(-2.f*x, -2.f*y, -2.f*z, (x*x + y*y) + z*z);
    float4 r1 = make_float4(-2.f*u, -2.f*v, -2.f*w, (u*u + v*v) + w*w);
    reinterpret_cast<float4*>(dst)[2*i]     = r0;
    reinterpret_cast<float4*>(dst)[2*i + 1] = r1;
}

// comparator on (Va,Ia): full exchange, ascending
#define CEX(V, I, A, B) { bool sw_ = V[B] < V[A];                       \
    float lo_ = sw_ ? V[B] : V[A]; float hi_ = sw_ ? V[A] : V[B];       \
    int   li_ = sw_ ? I[B] : I[A]; int   hj_ = sw_ ? I[A] : I[B];       \
    V[A] = lo_; V[B] = hi_; I[A] = li_; I[B] = hj_; }

// L lanes per fine point; chunks of 8 candidates per lane, unconditional
// Batcher sort8 + keep-low-8 bitonic merge with the running top-8.
template<int L>
__device__ __forceinline__ void topk_body(
    int vblk, const float* __restrict__ xyzF, const float* __restrict__ nrmF,
    const float* __restrict__ packC, int NF, int NC,
    int* __restrict__ outIdx, float* __restrict__ outW)
{
    const int lane = threadIdx.x & (L - 1);
    const int grp  = (vblk * 256 + (int)threadIdx.x) / L;   // [0, 2*NF)
    const int b    = grp >= NF ? 1 : 0;

    const float* fp = xyzF + (size_t)grp * 3;
    float fx = fp[0], fy = fp[1], fz = fp[2];
    const float* gp = nrmF + (size_t)grp * 3;
    float gx = gp[0], gy = gp[1], gz = gp[2];
    float sax = fmaf(fx, fx, fmaf(fy, fy, fz * fz));
    float san = fmaf(gx, gx, fmaf(gy, gy, gz * gz));

    float d[KNBR]; int id[KNBR];
#pragma unroll
    for (int j = 0; j < KNBR; ++j) { d[j] = 3.402823466e38f; id[j] = 0; }

    const float4* base = reinterpret_cast<const float4*>(packC) + (size_t)b * NC * 2;
    const int nch = NC / (8 * L);
    for (int cc = 0; cc < nch; ++cc) {
        const int s0 = cc * (8 * L) + lane;
        const float4* p = base + (size_t)s0 * 2;
        float4 q0[8], q1[8];
#pragma unroll
        for (int k = 0; k < 8; ++k) { q0[k] = p[2*L*k]; q1[k] = p[2*L*k + 1]; }

        float cv[8]; int ci[8];
#pragma unroll
        for (int k = 0; k < 8; ++k) {
            float d2  = fmaf(fx, q0[k].x, fmaf(fy, q0[k].y,
                        fmaf(fz, q0[k].z, sax + q0[k].w)));
            float dxx = __builtin_amdgcn_sqrtf(fmaxf(d2, 0.0f));
            float d2n = fmaf(gx, q1[k].x, fmaf(gy, q1[k].y,
                        fmaf(gz, q1[k].z, san + q1[k].w)));
            float dnn = __builtin_amdgcn_sqrtf(fmaxf(d2n, 0.0f));
            float sg  = __builtin_amdgcn_rcpf(1.0f + __expf(-dnn));
            cv[k] = dxx + sg;
            ci[k] = s0 + k * L;
        }

        // Batcher odd-even mergesort, 8 keys, 19 comparators -> ascending
        CEX(cv,ci,0,1) CEX(cv,ci,2,3) CEX(cv,ci,4,5) CEX(cv,ci,6,7)
        CEX(cv,ci,0,2) CEX(cv,ci,1,3) CEX(cv,ci,4,6) CEX(cv,ci,5,7)
        CEX(cv,ci,1,2) CEX(cv,ci,5,6)
        CEX(cv,ci,0,4) CEX(cv,ci,1,5) CEX(cv,ci,2,6) CEX(cv,ci,3,7)
        CEX(cv,ci,2,4) CEX(cv,ci,3,5)
        CEX(cv,ci,1,2) CEX(cv,ci,3,4) CEX(cv,ci,5,6)

        // keep-low-8 of (d asc, cv asc): lo[i]=min(d[i],cv[7-i]) -> bitonic
        float nd[KNBR]; int ni[KNBR];
#pragma unroll
        for (int i = 0; i < KNBR; ++i) {
            bool t = cv[KNBR-1-i] < d[i];
            nd[i] = t ? cv[KNBR-1-i] : d[i];
            ni[i] = t ? ci[KNBR-1-i] : id[i];
        }
        CEX(nd,ni,0,4) CEX(nd,ni,1,5) CEX(nd,ni,2,6) CEX(nd,ni,3,7)
        CEX(nd,ni,0,2) CEX(nd,ni,1,3) CEX(nd,ni,4,6) CEX(nd,ni,5,7)
        CEX(nd,ni,0,1) CEX(nd,ni,2,3) CEX(nd,ni,4,5) CEX(nd,ni,6,7)
#pragma unroll
        for (int j = 0; j < KNBR; ++j) { d[j] = nd[j]; id[j] = ni[j]; }
    }

    // merge sorted top-8 lists across the L-lane group (keep-low-8 bitonic)
#pragma unroll
    for (int m = 1; m < L; m <<= 1) {
        float pd[KNBR]; int pi[KNBR];
#pragma unroll
        for (int j = 0; j < KNBR; ++j) {
            pd[j] = __shfl_xor(d[j], m);
            pi[j] = __shfl_xor(id[j], m);
        }
        float nd[KNBR]; int ni[KNBR];
#pragma unroll
        for (int j = 0; j < KNBR; ++j) {
            bool t = pd[KNBR-1-j] < d[j];
            nd[j] = t ? pd[KNBR-1-j] : d[j];
            ni[j] = t ? pi[KNBR-1-j] : id[j];
        }
        CEX(nd,ni,0,4) CEX(nd,ni,1,5) CEX(nd,ni,2,6) CEX(nd,ni,3,7)
        CEX(nd,ni,0,2) CEX(nd,ni,1,3) CEX(nd,ni,4,6) CEX(nd,ni,5,7)
        CEX(nd,ni,0,1) CEX(nd,ni,2,3) CEX(nd,ni,4,5) CEX(nd,ni,6,7)
#pragma unroll
        for (int j = 0; j < KNBR; ++j) { d[j] = nd[j]; id[j] = ni[j]; }
    }

    if (lane == 0) {
        float r[KNBR]; float sum = 0.f;
#pragma unroll
        for (int j = 0; j < KNBR; ++j) { r[j] = 1.0f / (d[j] + 1e-8f); sum += r[j]; }
        int*   oi = outIdx + (size_t)grp * KNBR;
        float* ow = outW   + (size_t)grp * KNBR;
#pragma unroll
        for (int j = 0; j < KNBR; ++j) { oi[j] = id[j]; ow[j] = r[j] / sum; }
    }
}

// All three stages fused: blocks [0,G2) stage2, [G2,G2+G1) stage1, rest stage0.
// Stages are independent; fusing removes 2 launch gaps and co-schedules
// stage1/0 waves with stage2 (10.7k waves total ~ 10/SIMD).
#define G2 2048
#define G1 512
#define G0 128
__global__ __launch_bounds__(256) void topk_fused(
    const float* __restrict__ xyz0, const float* __restrict__ nrm0,
    const float* __restrict__ xyz1, const float* __restrict__ nrm1,
    const float* __restrict__ xyz2, const float* __restrict__ nrm2,
    const float* __restrict__ pack1, const float* __restrict__ pack2,
    const float* __restrict__ pack3,
    int* __restrict__ idx2, float* __restrict__ w2,
    int* __restrict__ idx1, float* __restrict__ w1,
    int* __restrict__ idx0, float* __restrict__ w0)
{
    const int blk = blockIdx.x;
    if (blk < G2)
        topk_body<16>(blk, xyz0, nrm0, pack1, 16384, 4096, idx2, w2);
    else if (blk < G2 + G1)
        topk_body<16>(blk - G2, xyz1, nrm1, pack2, 4096, 1024, idx1, w1);
    else
        topk_body<16>(blk - G2 - G1, xyz2, nrm2, pack3, 1024, 256, idx0, w0);
}

// 4 points per block; 64 lanes per point, float4 per lane (C=256).
__global__ __launch_bounds__(256) void interp_kernel(
    const float* __restrict__ p1, const float* __restrict__ p2,
    const int* __restrict__ idx, const float* __restrict__ w,
    int NF, int NC, float* __restrict__ out)
{
    const int pt = blockIdx.x * 4 + (threadIdx.x >> 6);  // [0, 2*NF), wave-uniform
    const int c4 = threadIdx.x & 63;
    const int b  = pt >= NF ? 1 : 0;
    const int*   ip = idx + (size_t)pt * KNBR;
    const float* wp = w   + (size_t)pt * KNBR;
    const float4* p2b = reinterpret_cast<const float4*>(p2) + (size_t)b * NC * 64;
    float4 acc = make_float4(0.f, 0.f, 0.f, 0.f);
#pragma unroll
    for (int j = 0; j < KNBR; ++j) {
        int   ii = ip[j];
        float ww = wp[j];
        float4 r = p2b[(size_t)ii * 64 + c4];
        acc.x += ww * r.x; acc.y += ww * r.y;
        acc.z += ww * r.z; acc.w += ww * r.w;
    }
    float4 a = reinterpret_cast<const float4*>(p1)[(size_t)pt * 64 + c4];
    float4 o;
    o.x = (fmaxf(a.x, acc.x) + (a.x + acc.x) * 0.5f) * 0.5f;
    o.y = (fmaxf(a.y, acc.y) + (a.y + acc.y) * 0.5f) * 0.5f;
    o.z = (fmaxf(a.z, acc.z) + (a.z + acc.z) * 0.5f) * 0.5f;
    o.w = (fmaxf(a.w, acc.w) + (a.w + acc.w) * 0.5f) * 0.5f;
    reinterpret_cast<float4*>(out)[(size_t)pt * 64 + c4] = o;
}

extern "C" void kernel_launch(void* const* d_in, const int* in_sizes, int n_in,
                              void* d_out, int out_size, void* d_ws, size_t ws_size,
                              hipStream_t stream)
{
    const float* xyz0  = (const float*)d_in[0];
    const float* nrm0  = (const float*)d_in[1];
    const float* feat0 = (const float*)d_in[2];
    const float* xyz1  = (const float*)d_in[3];
    const float* nrm1  = (const float*)d_in[4];
    const float* feat1 = (const float*)d_in[5];
    const float* xyz2  = (const float*)d_in[6];
    const float* nrm2  = (const float*)d_in[7];
    const float* feat2 = (const float*)d_in[8];
    const float* xyz3  = (const float*)d_in[9];
    const float* nrm3  = (const float*)d_in[10];
    const float* feat3 = (const float*)d_in[11];

    const int B = 2, C = 256;
    const int N0 = 16384, N1 = 4096, N2 = 1024, N3 = 256;

    float* ws = (float*)d_ws;
    size_t off = 0;
    float* pack1 = ws + off; off += (size_t)B*N1*8;   // coarse for stage 2
    float* pack2 = ws + off; off += (size_t)B*N2*8;   // coarse for stage 1
    float* pack3 = ws + off; off += (size_t)B*N3*8;   // coarse for stage 0
    int*   idx0  = (int*)(ws + off); off += (size_t)B*N2*KNBR;
    float* w0    = ws + off;         off += (size_t)B*N2*KNBR;
    int*   idx1  = (int*)(ws + off); off += (size_t)B*N1*KNBR;
    float* w1    = ws + off;         off += (size_t)B*N1*KNBR;
    int*   idx2  = (int*)(ws + off); off += (size_t)B*N0*KNBR;
    float* w2    = ws + off;         off += (size_t)B*N0*KNBR;
    float* x0    = ws + off;         off += (size_t)B*N2*C;
    float* x1    = ws + off;         off += (size_t)B*N1*C;

    int packTot = B * (N1 + N2 + N3);
    pack_kernel<<<(packTot + 255)/256, 256, 0, stream>>>(
        xyz1, nrm1, B*N1, xyz2, nrm2, B*N2, xyz3, nrm3, B*N3,
        pack1, pack2, pack3);

    topk_fused<<<G2 + G1 + G0, 256, 0, stream>>>(
        xyz0, nrm0, xyz1, nrm1, xyz2, nrm2,
        pack1, pack2, pack3, idx2, w2, idx1, w1, idx0, w0);

    // feature chain: feat3 -> x0 -> x1 -> d_out
    interp_kernel<<<(B*N2)/4, 256, 0, stream>>>(feat2, feat3, idx0, w0, N2, N3, x0);
    interp_kernel<<<(B*N1)/4, 256, 0, stream>>>(feat1, x0,    idx1, w1, N1, N2, x1);
    interp_kernel<<<(B*N0)/4, 256, 0, stream>>>(feat0, x1,    idx2, w2, N0, N1, (float*)d_out);
}

// Round 11
// 276.574 us; speedup vs baseline: 2.2232x; 1.0522x over previous
//
#include <hip/hip_runtime.h>

#define KNBR 8

// Pack each coarse point as {-2x,-2y,-2z,|xyz|^2, -2nx,-2ny,-2nz,|nrm|^2}
__global__ __launch_bounds__(256) void pack_kernel(
    const float* __restrict__ xa, const float* __restrict__ na, int ca,
    const float* __restrict__ xb, const float* __restrict__ nb, int cb,
    const float* __restrict__ xc, const float* __restrict__ nc_, int cc,
    float* __restrict__ pa, float* __restrict__ pb, float* __restrict__ pc)
{
#pragma clang fp contract(off)
    int t = blockIdx.x * blockDim.x + threadIdx.x;
    const float* xs; const float* ns; float* dst; int i;
    if (t < ca)            { xs = xa; ns = na;  dst = pa; i = t; }
    else if (t < ca + cb)  { xs = xb; ns = nb;  dst = pb; i = t - ca; }
    else if (t < ca+cb+cc) { xs = xc; ns = nc_; dst = pc; i = t - ca - cb; }
    else return;
    float x = xs[3*i], y = xs[3*i+1], z = xs[3*i+2];
    float u = ns[3*i], v = ns[3*i+1], w = ns[3*i+2];
    float4 r0 = make_float4(-2.f*x, -2.f*y, -2.f*z, (x*x + y*y) + z*z);
    float4 r1 = make_float4(-2.f*u, -2.f*v, -2.f*w, (u*u + v*v) + w*w);
    reinterpret_cast<float4*>(dst)[2*i]     = r0;
    reinterpret_cast<float4*>(dst)[2*i + 1] = r1;
}

// (u32 key, int origin) exchange, ascending — 5 insts
#define CEXU(V, I, A, B) { bool sw_ = V[B] < V[A];                        \
    unsigned lo_ = sw_ ? V[B] : V[A]; unsigned hi_ = sw_ ? V[A] : V[B];   \
    int li_ = sw_ ? I[B] : I[A]; int hj_ = sw_ ? I[A] : I[B];             \
    V[A] = lo_; V[B] = hi_; I[A] = li_; I[B] = hj_; }

// value-only u32 comparator — v_min_u32 + v_max_u32 (2 insts)
#define CEXVU(V, A, B) { unsigned lo_ = min(V[A], V[B]);                  \
    unsigned hi_ = max(V[A], V[B]); V[A] = lo_; V[B] = hi_; }

// 16 lanes/point. Keys: v = dx+sigmoid(dn) in [0.5,16) -> u = trunc(v*2^27)
// has exactly 24 significant bits => low 3 bits ALWAYS ZERO => key = u | k
// is LOSSLESS (order = (v, k), k = within-chunk slot; v recovered bit-exactly
// for weights). Chunk of 128 candidates staged in LDS, double-buffered,
// issue-early/write-late (T14); all 4 waves share the staged chunk.
__device__ __forceinline__ void topk_body16(
    int vblk, const float* __restrict__ xyzF, const float* __restrict__ nrmF,
    const float* __restrict__ packC, int NF, int NC,
    int* __restrict__ outIdx, float* __restrict__ outW,
    float4* sbuf /* [2*256] */)
{
    const int tid  = (int)threadIdx.x;
    const int lane = tid & 15;
    const int grp  = (vblk * 256 + tid) >> 4;    // [0, 2*NF)
    const int b    = grp >= NF ? 1 : 0;
    // staging role: wave w stages half h (q0/q1) of candidate group g
    const int sl = tid & 63, w = tid >> 6, h = w & 1, g = w >> 1;

    const float* fp = xyzF + (size_t)grp * 3;
    float fx = fp[0], fy = fp[1], fz = fp[2];
    const float* gp = nrmF + (size_t)grp * 3;
    float gx = gp[0], gy = gp[1], gz = gp[2];
    float sax = fmaf(fx, fx, fmaf(fy, fy, fz * fz));
    float san = fmaf(gx, gx, fmaf(gy, gy, gz * gz));

    unsigned d[KNBR]; int ib[KNBR];
#pragma unroll
    for (int j = 0; j < KNBR; ++j) { d[j] = 0xFFFFFFFFu; ib[j] = 0; }

    const float4* pc4 = reinterpret_cast<const float4*>(packC) + (size_t)b * NC * 2;
    const int nch = NC >> 7;                     // chunks of 128 candidates

    // prologue: stage chunk 0 into buffer 0
    sbuf[h * 128 + g * 64 + sl] = pc4[(size_t)(g * 64 + sl) * 2 + h];
    __syncthreads();

    int cur = 0;
    for (int cc = 0; cc < nch; ++cc) {
        // issue next chunk's load early (hides under compute)
        float4 st;
        const bool do_stage = (cc + 1 < nch);
        if (do_stage)
            st = pc4[(size_t)((cc + 1) * 128 + g * 64 + sl) * 2 + h];

        const float4* bq = sbuf + cur * 256;
        const int s0 = cc * 128 + lane;
        unsigned cv[8];
#pragma unroll
        for (int k = 0; k < 8; ++k) {
            float4 c0 = bq[lane + k * 16];           // q0 of candidate s0+k*16
            float4 c1 = bq[128 + lane + k * 16];     // q1
            float d2  = fmaf(fx, c0.x, fmaf(fy, c0.y, fmaf(fz, c0.z, sax + c0.w)));
            float dxx = __builtin_amdgcn_sqrtf(fmaxf(d2, 0.0f));
            float d2n = fmaf(gx, c1.x, fmaf(gy, c1.y, fmaf(gz, c1.z, san + c1.w)));
            float dnn = __builtin_amdgcn_sqrtf(fmaxf(d2n, 0.0f));
            float sg  = __builtin_amdgcn_rcpf(1.0f + __expf(-dnn));
            float v   = dxx + sg;                    // in [0.5, ~16)
            unsigned u = (unsigned)(v * 134217728.0f);  // v*2^27: low 3 bits = 0
            cv[k] = u | (unsigned)k;                 // lossless k embed
        }

        // Batcher sort8, values only (2-inst comparators)
        CEXVU(cv,0,1) CEXVU(cv,2,3) CEXVU(cv,4,5) CEXVU(cv,6,7)
        CEXVU(cv,0,2) CEXVU(cv,1,3) CEXVU(cv,4,6) CEXVU(cv,5,7)
        CEXVU(cv,1,2) CEXVU(cv,5,6)
        CEXVU(cv,0,4) CEXVU(cv,1,5) CEXVU(cv,2,6) CEXVU(cv,3,7)
        CEXVU(cv,2,4) CEXVU(cv,3,5)
        CEXVU(cv,1,2) CEXVU(cv,3,4) CEXVU(cv,5,6)

        // keep-low-8 with running top-8; origin = s0 (scalar for this chunk)
        unsigned nd[KNBR]; int ni[KNBR];
#pragma unroll
        for (int i = 0; i < KNBR; ++i) {
            bool t = cv[KNBR-1-i] < d[i];
            nd[i] = t ? cv[KNBR-1-i] : d[i];
            ni[i] = t ? s0 : ib[i];
        }
        CEXU(nd,ni,0,4) CEXU(nd,ni,1,5) CEXU(nd,ni,2,6) CEXU(nd,ni,3,7)
        CEXU(nd,ni,0,2) CEXU(nd,ni,1,3) CEXU(nd,ni,4,6) CEXU(nd,ni,5,7)
        CEXU(nd,ni,0,1) CEXU(nd,ni,2,3) CEXU(nd,ni,4,5) CEXU(nd,ni,6,7)
#pragma unroll
        for (int j = 0; j < KNBR; ++j) { d[j] = nd[j]; ib[j] = ni[j]; }

        // write-late: staged data lands just before the barrier
        if (do_stage)
            sbuf[(cur ^ 1) * 256 + h * 128 + g * 64 + sl] = st;
        __syncthreads();
        cur ^= 1;
    }

    // merge sorted top-8 across the 16-lane group (keep-low-8 bitonic)
#pragma unroll
    for (int m = 1; m < 16; m <<= 1) {
        unsigned pd[KNBR]; int pi[KNBR];
#pragma unroll
        for (int j = 0; j < KNBR; ++j) {
            pd[j] = (unsigned)__shfl_xor((int)d[j], m);
            pi[j] = __shfl_xor(ib[j], m);
        }
        unsigned nd[KNBR]; int ni[KNBR];
#pragma unroll
        for (int j = 0; j < KNBR; ++j) {
            bool t = pd[KNBR-1-j] < d[j];
            nd[j] = t ? pd[KNBR-1-j] : d[j];
            ni[j] = t ? pi[KNBR-1-j] : ib[j];
        }
        CEXU(nd,ni,0,4) CEXU(nd,ni,1,5) CEXU(nd,ni,2,6) CEXU(nd,ni,3,7)
        CEXU(nd,ni,0,2) CEXU(nd,ni,1,3) CEXU(nd,ni,4,6) CEXU(nd,ni,5,7)
        CEXU(nd,ni,0,1) CEXU(nd,ni,2,3) CEXU(nd,ni,4,5) CEXU(nd,ni,6,7)
#pragma unroll
        for (int j = 0; j < KNBR; ++j) { d[j] = nd[j]; ib[j] = ni[j]; }
    }

    if (lane == 0) {
        float r[KNBR]; float sum = 0.f;
        int   ix[KNBR];
#pragma unroll
        for (int j = 0; j < KNBR; ++j) {
            // exact v recovery: u has 24 significant bits -> cvt+mul exact
            float v = (float)(d[j] & ~7u) * 7.450580596923828e-9f;  // 2^-27
            ix[j] = ib[j] + (int)(d[j] & 7u) * 16;
            r[j] = 1.0f / (v + 1e-8f); sum += r[j];
        }
        int*   oi = outIdx + (size_t)grp * KNBR;
        float* ow = outW   + (size_t)grp * KNBR;
#pragma unroll
        for (int j = 0; j < KNBR; ++j) { oi[j] = ix[j]; ow[j] = r[j] / sum; }
    }
}

// All three stages fused: blocks [0,G2) stage2, [G2,G2+G1) stage1, rest stage0.
#define G2 2048
#define G1 512
#define G0 128
__global__ __launch_bounds__(256) void topk_fused(
    const float* __restrict__ xyz0, const float* __restrict__ nrm0,
    const float* __restrict__ xyz1, const float* __restrict__ nrm1,
    const float* __restrict__ xyz2, const float* __restrict__ nrm2,
    const float* __restrict__ pack1, const float* __restrict__ pack2,
    const float* __restrict__ pack3,
    int* __restrict__ idx2, float* __restrict__ w2,
    int* __restrict__ idx1, float* __restrict__ w1,
    int* __restrict__ idx0, float* __restrict__ w0)
{
    __shared__ float4 sbuf[2 * 256];   // 8 KB double-buffered chunk stage
    const int blk = blockIdx.x;
    if (blk < G2)
        topk_body16(blk, xyz0, nrm0, pack1, 16384, 4096, idx2, w2, sbuf);
    else if (blk < G2 + G1)
        topk_body16(blk - G2, xyz1, nrm1, pack2, 4096, 1024, idx1, w1, sbuf);
    else
        topk_body16(blk - G2 - G1, xyz2, nrm2, pack3, 1024, 256, idx0, w0, sbuf);
}

// 4 points per block; 64 lanes per point, float4 per lane (C=256).
__global__ __launch_bounds__(256) void interp_kernel(
    const float* __restrict__ p1, const float* __restrict__ p2,
    const int* __restrict__ idx, const float* __restrict__ w,
    int NF, int NC, float* __restrict__ out)
{
    const int pt = blockIdx.x * 4 + (threadIdx.x >> 6);  // [0, 2*NF), wave-uniform
    const int c4 = threadIdx.x & 63;
    const int b  = pt >= NF ? 1 : 0;
    const int*   ip = idx + (size_t)pt * KNBR;
    const float* wp = w   + (size_t)pt * KNBR;
    const float4* p2b = reinterpret_cast<const float4*>(p2) + (size_t)b * NC * 64;
    float4 acc = make_float4(0.f, 0.f, 0.f, 0.f);
#pragma unroll
    for (int j = 0; j < KNBR; ++j) {
        int   ii = ip[j];
        float ww = wp[j];
        float4 r = p2b[(size_t)ii * 64 + c4];
        acc.x += ww * r.x; acc.y += ww * r.y;
        acc.z += ww * r.z; acc.w += ww * r.w;
    }
    float4 a = reinterpret_cast<const float4*>(p1)[(size_t)pt * 64 + c4];
    float4 o;
    o.x = (fmaxf(a.x, acc.x) + (a.x + acc.x) * 0.5f) * 0.5f;
    o.y = (fmaxf(a.y, acc.y) + (a.y + acc.y) * 0.5f) * 0.5f;
    o.z = (fmaxf(a.z, acc.z) + (a.z + acc.z) * 0.5f) * 0.5f;
    o.w = (fmaxf(a.w, acc.w) + (a.w + acc.w) * 0.5f) * 0.5f;
    reinterpret_cast<float4*>(out)[(size_t)pt * 64 + c4] = o;
}

extern "C" void kernel_launch(void* const* d_in, const int* in_sizes, int n_in,
                              void* d_out, int out_size, void* d_ws, size_t ws_size,
                              hipStream_t stream)
{
    const float* xyz0  = (const float*)d_in[0];
    const float* nrm0  = (const float*)d_in[1];
    const float* feat0 = (const float*)d_in[2];
    const float* xyz1  = (const float*)d_in[3];
    const float* nrm1  = (const float*)d_in[4];
    const float* feat1 = (const float*)d_in[5];
    const float* xyz2  = (const float*)d_in[6];
    const float* nrm2  = (const float*)d_in[7];
    const float* feat2 = (const float*)d_in[8];
    const float* xyz3  = (const float*)d_in[9];
    const float* nrm3  = (const float*)d_in[10];
    const float* feat3 = (const float*)d_in[11];

    const int B = 2, C = 256;
    const int N0 = 16384, N1 = 4096, N2 = 1024, N3 = 256;

    float* ws = (float*)d_ws;
    size_t off = 0;
    float* pack1 = ws + off; off += (size_t)B*N1*8;
    float* pack2 = ws + off; off += (size_t)B*N2*8;
    float* pack3 = ws + off; off += (size_t)B*N3*8;
    int*   idx0  = (int*)(ws + off); off += (size_t)B*N2*KNBR;
    float* w0    = ws + off;         off += (size_t)B*N2*KNBR;
    int*   idx1  = (int*)(ws + off); off += (size_t)B*N1*KNBR;
    float* w1    = ws + off;         off += (size_t)B*N1*KNBR;
    int*   idx2  = (int*)(ws + off); off += (size_t)B*N0*KNBR;
    float* w2    = ws + off;         off += (size_t)B*N0*KNBR;
    float* x0    = ws + off;         off += (size_t)B*N2*C;
    float* x1    = ws + off;         off += (size_t)B*N1*C;

    int packTot = B * (N1 + N2 + N3);
    pack_kernel<<<(packTot + 255)/256, 256, 0, stream>>>(
        xyz1, nrm1, B*N1, xyz2, nrm2, B*N2, xyz3, nrm3, B*N3,
        pack1, pack2, pack3);

    topk_fused<<<G2 + G1 + G0, 256, 0, stream>>>(
        xyz0, nrm0, xyz1, nrm1, xyz2, nrm2,
        pack1, pack2, pack3, idx2, w2, idx1, w1, idx0, w0);

    // feature chain: feat3 -> x0 -> x1 -> d_out
    interp_kernel<<<(B*N2)/4, 256, 0, stream>>>(feat2, feat3, idx0, w0, N2, N3, x0);
    interp_kernel<<<(B*N1)/4, 256, 0, stream>>>(feat1, x0,    idx1, w1, N1, N2, x1);
    interp_kernel<<<(B*N0)/4, 256, 0, stream>>>(feat0, x1,    idx2, w2, N0, N1, (float*)d_out);
}

// Round 12
// 276.137 us; speedup vs baseline: 2.2267x; 1.0016x over previous
//
#include <hip/hip_runtime.h>

#define KNBR 8

// Pack each coarse point as {-2x,-2y,-2z,|xyz|^2, -2nx,-2ny,-2nz,|nrm|^2}
__global__ __launch_bounds__(256) void pack_kernel(
    const float* __restrict__ xa, const float* __restrict__ na, int ca,
    const float* __restrict__ xb, const float* __restrict__ nb, int cb,
    const float* __restrict__ xc, const float* __restrict__ nc_, int cc,
    float* __restrict__ pa, float* __restrict__ pb, float* __restrict__ pc)
{
#pragma clang fp contract(off)
    int t = blockIdx.x * blockDim.x + threadIdx.x;
    const float* xs; const float* ns; float* dst; int i;
    if (t < ca)            { xs = xa; ns = na;  dst = pa; i = t; }
    else if (t < ca + cb)  { xs = xb; ns = nb;  dst = pb; i = t - ca; }
    else if (t < ca+cb+cc) { xs = xc; ns = nc_; dst = pc; i = t - ca - cb; }
    else return;
    float x = xs[3*i], y = xs[3*i+1], z = xs[3*i+2];
    float u = ns[3*i], v = ns[3*i+1], w = ns[3*i+2];
    float4 r0 = make_float4(-2.f*x, -2.f*y, -2.f*z, (x*x + y*y) + z*z);
    float4 r1 = make_float4(-2.f*u, -2.f*v, -2.f*w, (u*u + v*v) + w*w);
    reinterpret_cast<float4*>(dst)[2*i]     = r0;
    reinterpret_cast<float4*>(dst)[2*i + 1] = r1;
}

// (u32 key, int origin) exchange, ascending — 5 insts
#define CEXU(V, I, A, B) { bool sw_ = V[B] < V[A];                        \
    unsigned lo_ = sw_ ? V[B] : V[A]; unsigned hi_ = sw_ ? V[A] : V[B];   \
    int li_ = sw_ ? I[B] : I[A]; int hj_ = sw_ ? I[A] : I[B];             \
    V[A] = lo_; V[B] = hi_; I[A] = li_; I[B] = hj_; }

// value-only u32 comparator — v_min_u32 + v_max_u32 (2 insts)
#define CEXVU(V, A, B) { unsigned lo_ = min(V[A], V[B]);                  \
    unsigned hi_ = max(V[A], V[B]); V[A] = lo_; V[B] = hi_; }

// 16 lanes/point. Keys: v = dx+sigmoid(dn) in [0.5,16) -> u = trunc(v*2^27)
// has exactly 24 significant bits => low 3 bits ALWAYS ZERO => key = u | k
// is LOSSLESS (order = (v, k), k = within-chunk slot; v recovered bit-exactly
// for weights). Chunk of 128 candidates staged in LDS, double-buffered,
// issue-early/write-late (T14); all 4 waves share the staged chunk.
__device__ __forceinline__ void topk_body16(
    int vblk, const float* __restrict__ xyzF, const float* __restrict__ nrmF,
    const float* __restrict__ packC, int NF, int NC,
    int* __restrict__ outIdx, float* __restrict__ outW,
    float4* sbuf /* [2*256] */)
{
    const int tid  = (int)threadIdx.x;
    const int lane = tid & 15;
    const int grp  = (vblk * 256 + tid) >> 4;    // [0, 2*NF)
    const int b    = grp >= NF ? 1 : 0;
    // staging role: wave w stages half h (q0/q1) of candidate group g
    const int sl = tid & 63, w = tid >> 6, h = w & 1, g = w >> 1;

    const float* fp = xyzF + (size_t)grp * 3;
    float fx = fp[0], fy = fp[1], fz = fp[2];
    const float* gp = nrmF + (size_t)grp * 3;
    float gx = gp[0], gy = gp[1], gz = gp[2];
    float sax = fmaf(fx, fx, fmaf(fy, fy, fz * fz));
    float san = fmaf(gx, gx, fmaf(gy, gy, gz * gz));

    unsigned d[KNBR]; int ib[KNBR];
#pragma unroll
    for (int j = 0; j < KNBR; ++j) { d[j] = 0xFFFFFFFFu; ib[j] = 0; }

    const float4* pc4 = reinterpret_cast<const float4*>(packC) + (size_t)b * NC * 2;
    const int nch = NC >> 7;                     // chunks of 128 candidates

    // prologue: stage chunk 0 into buffer 0
    sbuf[h * 128 + g * 64 + sl] = pc4[(size_t)(g * 64 + sl) * 2 + h];
    __syncthreads();

    int cur = 0;
    for (int cc = 0; cc < nch; ++cc) {
        // issue next chunk's load early (hides under compute)
        float4 st;
        const bool do_stage = (cc + 1 < nch);
        if (do_stage)
            st = pc4[(size_t)((cc + 1) * 128 + g * 64 + sl) * 2 + h];

        const float4* bq = sbuf + cur * 256;
        const int s0 = cc * 128 + lane;
        unsigned cv[8];
#pragma unroll
        for (int k = 0; k < 8; ++k) {
            float4 c0 = bq[lane + k * 16];           // q0 of candidate s0+k*16
            float4 c1 = bq[128 + lane + k * 16];     // q1
            float d2  = fmaf(fx, c0.x, fmaf(fy, c0.y, fmaf(fz, c0.z, sax + c0.w)));
            float dxx = __builtin_amdgcn_sqrtf(fmaxf(d2, 0.0f));
            float d2n = fmaf(gx, c1.x, fmaf(gy, c1.y, fmaf(gz, c1.z, san + c1.w)));
            float dnn = __builtin_amdgcn_sqrtf(fmaxf(d2n, 0.0f));
            float sg  = __builtin_amdgcn_rcpf(1.0f + __expf(-dnn));
            float v   = dxx + sg;                    // in [0.5, ~16)
            unsigned u = (unsigned)(v * 134217728.0f);  // v*2^27: low 3 bits = 0
            cv[k] = u | (unsigned)k;                 // lossless k embed
        }

        // Batcher sort8, values only (2-inst comparators)
        CEXVU(cv,0,1) CEXVU(cv,2,3) CEXVU(cv,4,5) CEXVU(cv,6,7)
        CEXVU(cv,0,2) CEXVU(cv,1,3) CEXVU(cv,4,6) CEXVU(cv,5,7)
        CEXVU(cv,1,2) CEXVU(cv,5,6)
        CEXVU(cv,0,4) CEXVU(cv,1,5) CEXVU(cv,2,6) CEXVU(cv,3,7)
        CEXVU(cv,2,4) CEXVU(cv,3,5)
        CEXVU(cv,1,2) CEXVU(cv,3,4) CEXVU(cv,5,6)

        // keep-low-8 with running top-8; origin = s0 (scalar for this chunk)
        unsigned nd[KNBR]; int ni[KNBR];
#pragma unroll
        for (int i = 0; i < KNBR; ++i) {
            bool t = cv[KNBR-1-i] < d[i];
            nd[i] = t ? cv[KNBR-1-i] : d[i];
            ni[i] = t ? s0 : ib[i];
        }
        CEXU(nd,ni,0,4) CEXU(nd,ni,1,5) CEXU(nd,ni,2,6) CEXU(nd,ni,3,7)
        CEXU(nd,ni,0,2) CEXU(nd,ni,1,3) CEXU(nd,ni,4,6) CEXU(nd,ni,5,7)
        CEXU(nd,ni,0,1) CEXU(nd,ni,2,3) CEXU(nd,ni,4,5) CEXU(nd,ni,6,7)
#pragma unroll
        for (int j = 0; j < KNBR; ++j) { d[j] = nd[j]; ib[j] = ni[j]; }

        // write-late: staged data lands just before the barrier
        if (do_stage)
            sbuf[(cur ^ 1) * 256 + h * 128 + g * 64 + sl] = st;
        __syncthreads();
        cur ^= 1;
    }

    // merge sorted top-8 across the 16-lane group (keep-low-8 bitonic)
#pragma unroll
    for (int m = 1; m < 16; m <<= 1) {
        unsigned pd[KNBR]; int pi[KNBR];
#pragma unroll
        for (int j = 0; j < KNBR; ++j) {
            pd[j] = (unsigned)__shfl_xor((int)d[j], m);
            pi[j] = __shfl_xor(ib[j], m);
        }
        unsigned nd[KNBR]; int ni[KNBR];
#pragma unroll
        for (int j = 0; j < KNBR; ++j) {
            bool t = pd[KNBR-1-j] < d[j];
            nd[j] = t ? pd[KNBR-1-j] : d[j];
            ni[j] = t ? pi[KNBR-1-j] : ib[j];
        }
        CEXU(nd,ni,0,4) CEXU(nd,ni,1,5) CEXU(nd,ni,2,6) CEXU(nd,ni,3,7)
        CEXU(nd,ni,0,2) CEXU(nd,ni,1,3) CEXU(nd,ni,4,6) CEXU(nd,ni,5,7)
        CEXU(nd,ni,0,1) CEXU(nd,ni,2,3) CEXU(nd,ni,4,5) CEXU(nd,ni,6,7)
#pragma unroll
        for (int j = 0; j < KNBR; ++j) { d[j] = nd[j]; ib[j] = ni[j]; }
    }

    if (lane == 0) {
        float r[KNBR]; float sum = 0.f;
        int   ix[KNBR];
#pragma unroll
        for (int j = 0; j < KNBR; ++j) {
            // exact v recovery: u has 24 significant bits -> cvt+mul exact
            float v = (float)(d[j] & ~7u) * 7.450580596923828e-9f;  // 2^-27
            ix[j] = ib[j] + (int)(d[j] & 7u) * 16;
            r[j] = 1.0f / (v + 1e-8f); sum += r[j];
        }
        int*   oi = outIdx + (size_t)grp * KNBR;
        float* ow = outW   + (size_t)grp * KNBR;
#pragma unroll
        for (int j = 0; j < KNBR; ++j) { oi[j] = ix[j]; ow[j] = r[j] / sum; }
    }
}

// All three stages fused: blocks [0,G2) stage2, [G2,G2+G1) stage1, rest stage0.
#define G2 2048
#define G1 512
#define G0 128
__global__ __launch_bounds__(256) void topk_fused(
    const float* __restrict__ xyz0, const float* __restrict__ nrm0,
    const float* __restrict__ xyz1, const float* __restrict__ nrm1,
    const float* __restrict__ xyz2, const float* __restrict__ nrm2,
    const float* __restrict__ pack1, const float* __restrict__ pack2,
    const float* __restrict__ pack3,
    int* __restrict__ idx2, float* __restrict__ w2,
    int* __restrict__ idx1, float* __restrict__ w1,
    int* __restrict__ idx0, float* __restrict__ w0)
{
    __shared__ float4 sbuf[2 * 256];   // 8 KB double-buffered chunk stage
    const int blk = blockIdx.x;
    if (blk < G2)
        topk_body16(blk, xyz0, nrm0, pack1, 16384, 4096, idx2, w2, sbuf);
    else if (blk < G2 + G1)
        topk_body16(blk - G2, xyz1, nrm1, pack2, 4096, 1024, idx1, w1, sbuf);
    else
        topk_body16(blk - G2 - G1, xyz2, nrm2, pack3, 1024, 256, idx0, w0, sbuf);
}

// 4 points per block; 64 lanes per point, float4 per lane (C=256).
// XCD-aware remap: MI355X dispatches blocks round-robin across 8 XCDs
// (xcd ~ blockIdx%8, each with a private 4MB L2). Map batch-0 points to
// XCDs 0-3 and batch-1 to XCDs 4-7 so each XCD's gather working set is ONE
// batch's p2 half (4MB for the final stage: x1 = 8MB total) -> L2-resident
// instead of thrashing to Infinity Cache. Pure permutation (bijective),
// requires gridDim.x % 8 == 0 (grids: 512/2048/8192).
__global__ __launch_bounds__(256) void interp_kernel(
    const float* __restrict__ p1, const float* __restrict__ p2,
    const int* __restrict__ idx, const float* __restrict__ w,
    int NF, int NC, float* __restrict__ out)
{
    const int bid  = (int)blockIdx.x;
    const int u    = bid >> 3, r = bid & 7;
    const int half = (int)(gridDim.x >> 1);           // blocks per batch
    const int lb   = (r < 4) ? (u * 4 + r) : (half + u * 4 + (r - 4));
    const int pt = lb * 4 + (threadIdx.x >> 6);       // [0, 2*NF), wave-uniform
    const int c4 = threadIdx.x & 63;
    const int b  = pt >= NF ? 1 : 0;
    const int*   ip = idx + (size_t)pt * KNBR;
    const float* wp = w   + (size_t)pt * KNBR;
    const float4* p2b = reinterpret_cast<const float4*>(p2) + (size_t)b * NC * 64;
    float4 acc = make_float4(0.f, 0.f, 0.f, 0.f);
#pragma unroll
    for (int j = 0; j < KNBR; ++j) {
        int   ii = ip[j];
        float ww = wp[j];
        float4 r4 = p2b[(size_t)ii * 64 + c4];
        acc.x += ww * r4.x; acc.y += ww * r4.y;
        acc.z += ww * r4.z; acc.w += ww * r4.w;
    }
    float4 a = reinterpret_cast<const float4*>(p1)[(size_t)pt * 64 + c4];
    float4 o;
    o.x = (fmaxf(a.x, acc.x) + (a.x + acc.x) * 0.5f) * 0.5f;
    o.y = (fmaxf(a.y, acc.y) + (a.y + acc.y) * 0.5f) * 0.5f;
    o.z = (fmaxf(a.z, acc.z) + (a.z + acc.z) * 0.5f) * 0.5f;
    o.w = (fmaxf(a.w, acc.w) + (a.w + acc.w) * 0.5f) * 0.5f;
    reinterpret_cast<float4*>(out)[(size_t)pt * 64 + c4] = o;
}

extern "C" void kernel_launch(void* const* d_in, const int* in_sizes, int n_in,
                              void* d_out, int out_size, void* d_ws, size_t ws_size,
                              hipStream_t stream)
{
    const float* xyz0  = (const float*)d_in[0];
    const float* nrm0  = (const float*)d_in[1];
    const float* feat0 = (const float*)d_in[2];
    const float* xyz1  = (const float*)d_in[3];
    const float* nrm1  = (const float*)d_in[4];
    const float* feat1 = (const float*)d_in[5];
    const float* xyz2  = (const float*)d_in[6];
    const float* nrm2  = (const float*)d_in[7];
    const float* feat2 = (const float*)d_in[8];
    const float* xyz3  = (const float*)d_in[9];
    const float* nrm3  = (const float*)d_in[10];
    const float* feat3 = (const float*)d_in[11];

    const int B = 2, C = 256;
    const int N0 = 16384, N1 = 4096, N2 = 1024, N3 = 256;

    float* ws = (float*)d_ws;
    size_t off = 0;
    float* pack1 = ws + off; off += (size_t)B*N1*8;
    float* pack2 = ws + off; off += (size_t)B*N2*8;
    float* pack3 = ws + off; off += (size_t)B*N3*8;
    int*   idx0  = (int*)(ws + off); off += (size_t)B*N2*KNBR;
    float* w0    = ws + off;         off += (size_t)B*N2*KNBR;
    int*   idx1  = (int*)(ws + off); off += (size_t)B*N1*KNBR;
    float* w1    = ws + off;         off += (size_t)B*N1*KNBR;
    int*   idx2  = (int*)(ws + off); off += (size_t)B*N0*KNBR;
    float* w2    = ws + off;         off += (size_t)B*N0*KNBR;
    float* x0    = ws + off;         off += (size_t)B*N2*C;
    float* x1    = ws + off;         off += (size_t)B*N1*C;

    int packTot = B * (N1 + N2 + N3);
    pack_kernel<<<(packTot + 255)/256, 256, 0, stream>>>(
        xyz1, nrm1, B*N1, xyz2, nrm2, B*N2, xyz3, nrm3, B*N3,
        pack1, pack2, pack3);

    topk_fused<<<G2 + G1 + G0, 256, 0, stream>>>(
        xyz0, nrm0, xyz1, nrm1, xyz2, nrm2,
        pack1, pack2, pack3, idx2, w2, idx1, w1, idx0, w0);

    // feature chain: feat3 -> x0 -> x1 -> d_out
    interp_kernel<<<(B*N2)/4, 256, 0, stream>>>(feat2, feat3, idx0, w0, N2, N3, x0);
    interp_kernel<<<(B*N1)/4, 256, 0, stream>>>(feat1, x0,    idx1, w1, N1, N2, x1);
    interp_kernel<<<(B*N0)/4, 256, 0, stream>>>(feat0, x1,    idx2, w2, N0, N1, (float*)d_out);
}